// Round 5
// baseline (544.949 us; speedup 1.0000x reference)
//
#include <hip/hip_runtime.h>

#define PI_F 3.14159265358979323846f

// clang ext_vector_type: __builtin_nontemporal_store requires a pointer to a
// builtin scalar/vector type (HIP's float2/float4 classes are NOT accepted).
typedef float f32x4 __attribute__((ext_vector_type(4)));

// ---------------------------------------------------------------------------
// Kernel 1: per-batch matrix build + analytic 3x3 (affine) inverse.
// ---------------------------------------------------------------------------
__global__ void build_mats_kernel(const float* __restrict__ fc2,
                                  float* __restrict__ mat_out,
                                  float* __restrict__ inv_out,
                                  int B) {
    int b = blockIdx.x * blockDim.x + threadIdx.x;
    if (b >= B) return;
    const float* f = fc2 + b * 7;
    float theta = fminf(fmaxf(f[0] * 0.3f, -1.f), 1.f) * PI_F;
    float sx    = fminf(fmaxf(f[1] * 0.3f + 1.f, 0.f), 5.f);
    float sy    = fminf(fmaxf(f[2] * 0.3f + 1.f, 0.f), 5.f);
    float tx    = f[3] * 0.3f;
    float ty    = f[4] * 0.3f;
    float shxy  = fminf(fmaxf(f[5] * 0.3f, -1.f), 1.f) * PI_F;
    float shyx  = fminf(fmaxf(f[6] * 0.3f, -1.f), 1.f) * PI_F;

    float c = cosf(theta), s = sinf(theta);
    float m00 =  sx * c + shxy * sy * s;
    float m01 = -sx * s + shxy * sy * c;
    float m02 = tx;
    float m10 = shyx * sx * c + sy * s;
    float m11 = -shyx * sx * s + sy * c;
    float m12 = ty;

    float* m = mat_out + b * 9;
    m[0] = m00; m[1] = m01; m[2] = m02;
    m[3] = m10; m[4] = m11; m[5] = m12;
    m[6] = 0.f; m[7] = 0.f; m[8] = 1.f;

    // Affine inverse: [[A^-1, -A^-1 t],[0,0,1]]
    float det = m00 * m11 - m01 * m10;
    float id  = 1.f / det;
    float i00 =  m11 * id, i01 = -m01 * id;
    float i10 = -m10 * id, i11 =  m00 * id;
    float i02 = -(i00 * m02 + i01 * m12);
    float i12 = -(i10 * m02 + i11 * m12);

    float* im = inv_out + b * 9;
    im[0] = i00; im[1] = i01; im[2] = i02;
    im[3] = i10; im[4] = i11; im[5] = i12;
    im[6] = 0.f; im[7] = 0.f; im[8] = 1.f;
}

// ---------------------------------------------------------------------------
// Kernel 2: PURE STREAMING grid writer (unchanged from R3). fillBuffer shows
// pure writes hit 6.5 TB/s on this machine; this kernel is built to match it:
// one block per (row,batch), 16B f32x4 nontemporal stores, full-line writes,
// wave-uniform matrices via s_load.
// ---------------------------------------------------------------------------
__global__ __launch_bounds__(256) void grid_kernel(
    const float* __restrict__ mat,
    const float* __restrict__ inv_mat,
    float* __restrict__ grid_out,
    float* __restrict__ inv_grid_out)
{
    const int W = 512, H = 512;
    const int h = blockIdx.x;
    const int b = blockIdx.y;
    const int w = threadIdx.x * 2;

    float xs0 = (2.f * (float)w + 1.f) * (1.f / (float)W) - 1.f;
    float xs1 = xs0 + 2.f / (float)W;
    float ys  = (2.f * (float)h + 1.f) * (1.f / (float)H) - 1.f;

    const float* m  = mat + b * 9;
    const float* im = inv_mat + b * 9;

    float gx0  = m[0] * xs0 + (m[1] * ys + m[2]);
    float gy0  = m[3] * xs0 + (m[4] * ys + m[5]);
    float gx1  = m[0] * xs1 + (m[1] * ys + m[2]);
    float gy1  = m[3] * xs1 + (m[4] * ys + m[5]);
    float igx0 = im[0] * xs0 + (im[1] * ys + im[2]);
    float igy0 = im[3] * xs0 + (im[4] * ys + im[5]);
    float igx1 = im[0] * xs1 + (im[1] * ys + im[2]);
    float igy1 = im[3] * xs1 + (im[4] * ys + im[5]);

    size_t vec = ((size_t)b * H + h) * (W / 2) + threadIdx.x;  // f32x4 index
    f32x4 g  = {gx0, gy0, gx1, gy1};
    f32x4 ig = {igx0, igy0, igx1, igy1};
    __builtin_nontemporal_store(g,  (f32x4*)grid_out + vec);
    __builtin_nontemporal_store(ig, (f32x4*)inv_grid_out + vec);
}

// ---------------------------------------------------------------------------
// Kernel 3: LDS-staged bilinear sampler. Block (16,16,1) = 16x16 output tile.
// The tile's src footprint (bbox of the 4 affine-mapped corners, +1px margin
// for bilinear taps & fp rounding, clamped to the image) is staged into LDS
// with coalesced full-line global reads ONCE; the 16 taps/pixel (4 taps x
// 4 channels) then hit LDS at ~4-6 cyc instead of ~20 L1 line-transactions
// per gather instruction (the measured ~2 TB/s effective gather ceiling).
// Typical footprint: ~25x25 px x 4ch = 10 KB. CAP=2048 floats/ch (32 KB LDS,
// 5 blocks/CU) covers scale up to ~2.7; larger (P~1e-6 tail of clip(0.3N+1),
// needed for correctness) falls back block-uniformly to the global path.
// bbox containment: ix is affine in (w,h) so min/max over corners bounds all
// pixels; clamped tap coords land in the clamped bbox (see margin note).
// ---------------------------------------------------------------------------
__global__ __launch_bounds__(256) void sample_kernel(
    const float* __restrict__ src,
    const float* __restrict__ mat,
    float* __restrict__ transformed)
{
    const int W = 512, H = 512;
    constexpr int CAP = 2048;                 // floats per channel
    __shared__ float tile[4][CAP];            // 32 KB

    const int tx = threadIdx.x, ty = threadIdx.y;
    const int w0 = blockIdx.x * 16, h0 = blockIdx.y * 16;
    const int b  = blockIdx.z;
    const int w = w0 + tx, h = h0 + ty;

    const float* m = mat + b * 9;             // blockIdx.z uniform -> s_load
    const float m0 = m[0], m1 = m[1], m2 = m[2];
    const float m3 = m[3], m4 = m[4], m5 = m[5];

    // ---- block-uniform src bbox from the 4 tile corners ----
    float minix = 1e30f, maxix = -1e30f, miniy = 1e30f, maxiy = -1e30f;
    #pragma unroll
    for (int j = 0; j < 2; ++j) {
        #pragma unroll
        for (int i = 0; i < 2; ++i) {
            float xs = (2.f * (float)(w0 + i * 15) + 1.f) * (1.f / (float)W) - 1.f;
            float ys = (2.f * (float)(h0 + j * 15) + 1.f) * (1.f / (float)H) - 1.f;
            float gx = m0 * xs + (m1 * ys + m2);
            float gy = m3 * xs + (m4 * ys + m5);
            float cix = ((gx + 1.f) * (float)W - 1.f) * 0.5f;
            float ciy = ((gy + 1.f) * (float)H - 1.f) * 0.5f;
            minix = fminf(minix, cix); maxix = fmaxf(maxix, cix);
            miniy = fminf(miniy, ciy); maxiy = fmaxf(maxiy, ciy);
        }
    }
    // -1/+2 margin: +1 covers the x0+1 tap, +/-1 absorbs per-pixel fp jitter.
    // Clamping keeps all clamped tap coords inside [bx0,bx1]x[by0,by1].
    const int bx0 = min(max((int)floorf(minix) - 1, 0), W - 1);
    const int bx1 = min(max((int)floorf(maxix) + 2, 0), W - 1);
    const int by0 = min(max((int)floorf(miniy) - 1, 0), H - 1);
    const int by1 = min(max((int)floorf(maxiy) + 2, 0), H - 1);
    const int bw  = bx1 - bx0 + 1, bh = by1 - by0 + 1;
    const int bwp = bw | 1;                   // odd LDS stride -> bank spread
    const bool staged = (bh * bwp) <= CAP;    // block-uniform branch

    if (staged) {
        #pragma unroll
        for (int c = 0; c < 4; ++c) {
            const float* sp = src + ((size_t)b * 4 + c) * H * W;
            for (int yy = ty; yy < bh; yy += 16)
                for (int xx = tx; xx < bw; xx += 16)
                    tile[c][yy * bwp + xx] = sp[(by0 + yy) * W + (bx0 + xx)];
        }
        __syncthreads();
    }

    // ---- per-pixel bilinear (align_corners=False, identical formula) ----
    float xs = (2.f * (float)w + 1.f) * (1.f / (float)W) - 1.f;
    float ys = (2.f * (float)h + 1.f) * (1.f / (float)H) - 1.f;
    float gx = m0 * xs + (m1 * ys + m2);
    float gy = m3 * xs + (m4 * ys + m5);

    float ix = ((gx + 1.f) * (float)W - 1.f) * 0.5f;
    float iy = ((gy + 1.f) * (float)H - 1.f) * 0.5f;
    float x0f = floorf(ix), y0f = floorf(iy);
    float wx = ix - x0f, wy = iy - y0f;
    int x0 = (int)x0f, y0 = (int)y0f;
    int x1 = x0 + 1,   y1 = y0 + 1;

    bool vx0 = (x0 >= 0) && (x0 < W);
    bool vx1 = (x1 >= 0) && (x1 < W);
    bool vy0 = (y0 >= 0) && (y0 < H);
    bool vy1 = (y1 >= 0) && (y1 < H);
    int cx0 = min(max(x0, 0), W - 1), cx1 = min(max(x1, 0), W - 1);
    int cy0 = min(max(y0, 0), H - 1), cy1 = min(max(y1, 0), H - 1);

    float w00 = (1.f - wx) * (1.f - wy) * ((vx0 && vy0) ? 1.f : 0.f);
    float w01 = wx * (1.f - wy)         * ((vx1 && vy0) ? 1.f : 0.f);
    float w10 = (1.f - wx) * wy         * ((vx0 && vy1) ? 1.f : 0.f);
    float w11 = wx * wy                 * ((vx1 && vy1) ? 1.f : 0.f);

    if (staged) {
        int r0 = (cy0 - by0) * bwp - bx0;
        int r1 = (cy1 - by0) * bwp - bx0;
        int l00 = r0 + cx0, l01 = r0 + cx1;
        int l10 = r1 + cx0, l11 = r1 + cx1;
        #pragma unroll
        for (int c = 0; c < 4; ++c) {
            float v = tile[c][l00] * w00 + tile[c][l01] * w01
                    + tile[c][l10] * w10 + tile[c][l11] * w11;
            __builtin_nontemporal_store(
                v, transformed + (((size_t)b * 4 + c) * H + h) * W + w);
        }
    } else {
        const float* sb = src + (size_t)b * 4 * H * W;
        int o00 = cy0 * W + cx0;
        int o01 = cy0 * W + cx1;
        int o10 = cy1 * W + cx0;
        int o11 = cy1 * W + cx1;
        #pragma unroll
        for (int c = 0; c < 4; ++c) {
            const float* sc = sb + c * (H * W);
            float v = sc[o00] * w00 + sc[o01] * w01
                    + sc[o10] * w10 + sc[o11] * w11;
            __builtin_nontemporal_store(
                v, transformed + (((size_t)b * 4 + c) * H + h) * W + w);
        }
    }
}

extern "C" void kernel_launch(void* const* d_in, const int* in_sizes, int n_in,
                              void* d_out, int out_size, void* d_ws, size_t ws_size,
                              hipStream_t stream) {
    const float* src = (const float*)d_in[0];   // (32,4,512,512) f32
    const float* fc2 = (const float*)d_in[1];   // (32,7) f32

    const int B = 32, C = 4, H = 512, W = 512;
    float* out = (float*)d_out;

    // Output layout (flat, return order):
    float* transformed  = out;                                   // 33,554,432
    float* mat_out      = out + (size_t)B * C * H * W;           // +288
    float* inv_out      = mat_out + (size_t)B * 9;               // +288
    float* grid_out     = inv_out + (size_t)B * 9;               // +16,777,216
    float* inv_grid_out = grid_out + (size_t)B * H * W * 2;      // +16,777,216

    // Kernel 1: 32 matrices
    build_mats_kernel<<<1, 64, 0, stream>>>(fc2, mat_out, inv_out, B);

    // Kernel 2: pure-streaming grid + inv_grid writer (one row per block)
    grid_kernel<<<dim3(H, B), 256, 0, stream>>>(mat_out, inv_out,
                                                grid_out, inv_grid_out);

    // Kernel 3: LDS-staged bilinear sampler, 16x16 tiles
    sample_kernel<<<dim3(W / 16, H / 16, B), dim3(16, 16, 1), 0, stream>>>(
        src, mat_out, transformed);
}

// Round 6
// 408.745 us; speedup vs baseline: 1.3332x; 1.3332x over previous
//
#include <hip/hip_runtime.h>

#define PI_F 3.14159265358979323846f

// clang ext_vector_type: __builtin_nontemporal_store requires a pointer to a
// builtin scalar/vector type (HIP's float2/float4 classes are NOT accepted).
typedef float f32x4 __attribute__((ext_vector_type(4)));

// ---------------------------------------------------------------------------
// Kernel 1: per-batch matrix build + analytic 3x3 (affine) inverse.
// ---------------------------------------------------------------------------
__global__ void build_mats_kernel(const float* __restrict__ fc2,
                                  float* __restrict__ mat_out,
                                  float* __restrict__ inv_out,
                                  int B) {
    int b = blockIdx.x * blockDim.x + threadIdx.x;
    if (b >= B) return;
    const float* f = fc2 + b * 7;
    float theta = fminf(fmaxf(f[0] * 0.3f, -1.f), 1.f) * PI_F;
    float sx    = fminf(fmaxf(f[1] * 0.3f + 1.f, 0.f), 5.f);
    float sy    = fminf(fmaxf(f[2] * 0.3f + 1.f, 0.f), 5.f);
    float tx    = f[3] * 0.3f;
    float ty    = f[4] * 0.3f;
    float shxy  = fminf(fmaxf(f[5] * 0.3f, -1.f), 1.f) * PI_F;
    float shyx  = fminf(fmaxf(f[6] * 0.3f, -1.f), 1.f) * PI_F;

    float c = cosf(theta), s = sinf(theta);
    float m00 =  sx * c + shxy * sy * s;
    float m01 = -sx * s + shxy * sy * c;
    float m02 = tx;
    float m10 = shyx * sx * c + sy * s;
    float m11 = -shyx * sx * s + sy * c;
    float m12 = ty;

    float* m = mat_out + b * 9;
    m[0] = m00; m[1] = m01; m[2] = m02;
    m[3] = m10; m[4] = m11; m[5] = m12;
    m[6] = 0.f; m[7] = 0.f; m[8] = 1.f;

    // Affine inverse: [[A^-1, -A^-1 t],[0,0,1]]
    float det = m00 * m11 - m01 * m10;
    float id  = 1.f / det;
    float i00 =  m11 * id, i01 = -m01 * id;
    float i10 = -m10 * id, i11 =  m00 * id;
    float i02 = -(i00 * m02 + i01 * m12);
    float i12 = -(i10 * m02 + i11 * m12);

    float* im = inv_out + b * 9;
    im[0] = i00; im[1] = i01; im[2] = i02;
    im[3] = i10; im[4] = i11; im[5] = i12;
    im[6] = 0.f; im[7] = 0.f; im[8] = 1.f;
}

// ---------------------------------------------------------------------------
// Kernel 2: block-specialized fused kernel.
// R5 lesson: LDS staging of the gather REGRESSED (occupancy 37%, +32MB
// over-fetch, staging pays the L1 cost the taps were already paying) —
// the gather's FETCH was already = unique src bytes; its cost is L1
// tag/transaction replay, NOT HBM. So: keep the R3/R4 global-gather form.
// R4 lesson: split kernels serialize a ~126us L1-transaction-bound phase
// (sampler) after a ~58us HBM-write-bound phase (grid writer) — different
// resources, zero overlap. Fix: ONE kernel, every 5th block is a pure
// streaming grid/inv_grid writer, the other 4/5 are gather/sample blocks.
// Interleaved blockIdx co-locates both kinds on each CU, so the writers'
// 128MB of full-line nt stores flow while sampler waves occupy the L1 path.
// Expected: total ~= max(gather-bound, write-bound) instead of the sum.
// ---------------------------------------------------------------------------
__global__ __launch_bounds__(256) void fused_kernel(
    const float* __restrict__ src,
    const float* __restrict__ mat,
    const float* __restrict__ inv_mat,
    float* __restrict__ transformed,
    float* __restrict__ grid_out,
    float* __restrict__ inv_grid_out)
{
    const int W = 512, H = 512;
    const int bid = blockIdx.x;
    const int q = bid / 5, r = bid - q * 5;

    if (r == 4) {
        // ---- grid-writer block: widx in [0,8192) -> batch b, 2 rows ----
        const int widx = q;
        const int b  = widx >> 8;           // 32 batches
        const int rp = widx & 255;          // 256 row-pairs
        const int t  = threadIdx.x;         // 0..255, one f32x4 (2 px) each

        const float* m  = mat + b * 9;      // uniform -> s_load
        const float* im = inv_mat + b * 9;
        const float m0 = m[0],  m1 = m[1],  m2 = m[2];
        const float m3 = m[3],  m4 = m[4],  m5 = m[5];
        const float i0 = im[0], i1 = im[1], i2 = im[2];
        const float i3 = im[3], i4 = im[4], i5 = im[5];

        float xs0 = (2.f * (float)(2 * t) + 1.f) * (1.f / (float)W) - 1.f;
        float xs1 = xs0 + 2.f / (float)W;

        #pragma unroll
        for (int rr = 0; rr < 2; ++rr) {
            int h = rp * 2 + rr;
            float ys = (2.f * (float)h + 1.f) * (1.f / (float)H) - 1.f;
            f32x4 g  = {m0 * xs0 + (m1 * ys + m2), m3 * xs0 + (m4 * ys + m5),
                        m0 * xs1 + (m1 * ys + m2), m3 * xs1 + (m4 * ys + m5)};
            f32x4 ig = {i0 * xs0 + (i1 * ys + i2), i3 * xs0 + (i4 * ys + i5),
                        i0 * xs1 + (i1 * ys + i2), i3 * xs1 + (i4 * ys + i5)};
            size_t vec = ((size_t)b * H + h) * (W / 2) + t;   // f32x4 index
            __builtin_nontemporal_store(g,  (f32x4*)grid_out + vec);
            __builtin_nontemporal_store(ig, (f32x4*)inv_grid_out + vec);
        }
        return;
    }

    // ---- sampler block: sidx in [0,32768) -> (b, 16x16 tile) ----
    const int sidx = q * 4 + r;
    const int b   = sidx >> 10;             // 32 batches
    const int rem = sidx & 1023;            // 32x32 tiles
    const int w0 = (rem & 31) * 16, h0 = (rem >> 5) * 16;

    // 8x8 px per wave (R3-proven: FETCH == unique bytes for any rotation)
    const int t    = threadIdx.x;
    const int wave = t >> 6, lane = t & 63;
    const int w = w0 + (wave & 1) * 8 + (lane & 7);
    const int h = h0 + (wave >> 1) * 8 + (lane >> 3);

    const float* m = mat + b * 9;           // uniform -> s_load
    float xs = (2.f * (float)w + 1.f) * (1.f / (float)W) - 1.f;
    float ys = (2.f * (float)h + 1.f) * (1.f / (float)H) - 1.f;
    float gx = m[0] * xs + (m[1] * ys + m[2]);
    float gy = m[3] * xs + (m[4] * ys + m[5]);

    // Bilinear sample (align_corners=False convention per reference)
    float ix = ((gx + 1.f) * (float)W - 1.f) * 0.5f;
    float iy = ((gy + 1.f) * (float)H - 1.f) * 0.5f;
    float x0f = floorf(ix), y0f = floorf(iy);
    float wx = ix - x0f, wy = iy - y0f;
    int x0 = (int)x0f, y0 = (int)y0f;
    int x1 = x0 + 1,   y1 = y0 + 1;

    bool vx0 = (x0 >= 0) && (x0 < W);
    bool vx1 = (x1 >= 0) && (x1 < W);
    bool vy0 = (y0 >= 0) && (y0 < H);
    bool vy1 = (y1 >= 0) && (y1 < H);
    int cx0 = min(max(x0, 0), W - 1), cx1 = min(max(x1, 0), W - 1);
    int cy0 = min(max(y0, 0), H - 1), cy1 = min(max(y1, 0), H - 1);

    float w00 = (1.f - wx) * (1.f - wy) * ((vx0 && vy0) ? 1.f : 0.f);
    float w01 = wx * (1.f - wy)         * ((vx1 && vy0) ? 1.f : 0.f);
    float w10 = (1.f - wx) * wy         * ((vx0 && vy1) ? 1.f : 0.f);
    float w11 = wx * wy                 * ((vx1 && vy1) ? 1.f : 0.f);

    const float* sb = src + (size_t)b * 4 * H * W;
    // 32-bit offsets: per-batch plane is 4*512*512 floats < 2^31
    int o00 = cy0 * W + cx0;
    int o01 = cy0 * W + cx1;
    int o10 = cy1 * W + cx0;
    int o11 = cy1 * W + cx1;

    #pragma unroll
    for (int c = 0; c < 4; ++c) {
        const float* sc = sb + c * (H * W);
        float v = sc[o00] * w00 + sc[o01] * w01 + sc[o10] * w10 + sc[o11] * w11;
        __builtin_nontemporal_store(
            v, transformed + (((size_t)b * 4 + c) * H + h) * W + w);
    }
}

extern "C" void kernel_launch(void* const* d_in, const int* in_sizes, int n_in,
                              void* d_out, int out_size, void* d_ws, size_t ws_size,
                              hipStream_t stream) {
    const float* src = (const float*)d_in[0];   // (32,4,512,512) f32
    const float* fc2 = (const float*)d_in[1];   // (32,7) f32

    const int B = 32, C = 4, H = 512, W = 512;
    float* out = (float*)d_out;

    // Output layout (flat, return order):
    float* transformed  = out;                                   // 33,554,432
    float* mat_out      = out + (size_t)B * C * H * W;           // +288
    float* inv_out      = mat_out + (size_t)B * 9;               // +288
    float* grid_out     = inv_out + (size_t)B * 9;               // +16,777,216
    float* inv_grid_out = grid_out + (size_t)B * H * W * 2;      // +16,777,216

    // Kernel 1: 32 matrices
    build_mats_kernel<<<1, 64, 0, stream>>>(fc2, mat_out, inv_out, B);

    // Kernel 2: fused — 32768 sampler blocks + 8192 grid-writer blocks,
    // interleaved 4:1 so both kinds are co-resident on every CU.
    fused_kernel<<<dim3(40960), dim3(256), 0, stream>>>(
        src, mat_out, inv_out, transformed, grid_out, inv_grid_out);
}